// Round 1
// baseline (754.882 us; speedup 1.0000x reference)
//
#include <hip/hip_runtime.h>

#define IN_DIM     1024
#define OUTPUT_DIM 512
#define N_ROWS     131072

// One 64-lane wave per row. Each lane:
//   - loads 2 float4 from x[row, 512:1024]  (8 floats)  -> partial sum
//   - butterfly shfl_xor reduce over 64 lanes            -> row sum
//   - loads 2 float4 from x[row, 0:512], adds mean, stores 2 float4
// All global accesses: lane i touches float4 index (base + i) -> 16B/lane,
// fully coalesced.
__global__ __launch_bounds__(256) void proj_kernel(const float* __restrict__ x,
                                                   float* __restrict__ out,
                                                   int n_rows) {
    const int lane            = threadIdx.x & 63;
    const int wave_in_block   = threadIdx.x >> 6;
    const int waves_per_block = blockDim.x >> 6;          // 4
    const int wave_global     = blockIdx.x * waves_per_block + wave_in_block;
    const int total_waves     = gridDim.x * waves_per_block;

    for (int row = wave_global; row < n_rows; row += total_waves) {
        const float4* xr = reinterpret_cast<const float4*>(x + (size_t)row * IN_DIM);

        // Issue all 4 loads up front so HBM latency overlaps the reduce.
        float4 c = xr[lane];             // first half  [0..255]
        float4 d = xr[64 + lane];
        float4 a = xr[128 + lane];       // second half [128..255] in float4 units
        float4 b = xr[192 + lane];

        float s = (a.x + a.y) + (a.z + a.w) + (b.x + b.y) + (b.z + b.w);

        // 64-lane butterfly reduction (wave = 64 on CDNA).
        #pragma unroll
        for (int off = 32; off > 0; off >>= 1)
            s += __shfl_xor(s, off, 64);

        s *= (1.0f / OUTPUT_DIM);        // mean over the 512 tail elements

        c.x += s; c.y += s; c.z += s; c.w += s;
        d.x += s; d.y += s; d.z += s; d.w += s;

        float4* o = reinterpret_cast<float4*>(out + (size_t)row * OUTPUT_DIM);
        o[lane]      = c;
        o[64 + lane] = d;
    }
}

extern "C" void kernel_launch(void* const* d_in, const int* in_sizes, int n_in,
                              void* d_out, int out_size, void* d_ws, size_t ws_size,
                              hipStream_t stream) {
    const float* x   = (const float*)d_in[0];
    float*       out = (float*)d_out;

    const int n_rows = in_sizes[0] / IN_DIM;   // 131072

    // Memory-bound: cap grid ~2048 blocks, grid-stride the rest (G11).
    const int block = 256;                      // 4 waves/block
    const int waves_needed = n_rows;            // 1 wave per row
    int grid = (waves_needed + 3) / 4;          // blocks if no striding
    if (grid > 2048) grid = 2048;

    proj_kernel<<<grid, block, 0, stream>>>(x, out, n_rows);
}

// Round 2
// 723.374 us; speedup vs baseline: 1.0436x; 1.0436x over previous
//
#include <hip/hip_runtime.h>

#define IN_DIM     1024
#define OUTPUT_DIM 512

// Native vector type so __builtin_nontemporal_load/store apply.
typedef float v4f __attribute__((ext_vector_type(4)));

constexpr int ROWS_PER_WAVE = 4;

// One 64-lane wave per row, 4 consecutive rows per wave (fully unrolled so
// all 16 global loads can be in flight together). Per row:
//   - 2x float4 from x[row, 512:1024] -> partial sum -> 64-lane butterfly
//   - 2x float4 from x[row, 0:512] + mean -> 2x float4 store
// Streaming data (768 MiB > L3): nontemporal loads/stores to avoid cache
// allocation / write-allocate on never-reused lines.
__global__ __launch_bounds__(256) void proj_kernel(const float* __restrict__ x,
                                                   float* __restrict__ out,
                                                   int n_rows) {
    const int lane = threadIdx.x & 63;
    const int wave = blockIdx.x * (blockDim.x >> 6) + (threadIdx.x >> 6);
    const int row0 = wave * ROWS_PER_WAVE;
    if (row0 >= n_rows) return;

    const v4f* xr = reinterpret_cast<const v4f*>(x)   + (size_t)row0 * (IN_DIM / 4);
    v4f*       o  = reinterpret_cast<v4f*>(out)       + (size_t)row0 * (OUTPUT_DIM / 4);

    #pragma unroll
    for (int t = 0; t < ROWS_PER_WAVE; ++t) {
        const v4f* xrow = xr + t * (IN_DIM / 4);

        // Issue all 4 row loads up front; independent across t as well.
        v4f c = __builtin_nontemporal_load(&xrow[lane]);        // first half
        v4f d = __builtin_nontemporal_load(&xrow[64 + lane]);
        v4f a = __builtin_nontemporal_load(&xrow[128 + lane]);  // second half
        v4f b = __builtin_nontemporal_load(&xrow[192 + lane]);

        float s = (a.x + a.y) + (a.z + a.w) + (b.x + b.y) + (b.z + b.w);

        // 64-lane butterfly reduction (wave = 64 on CDNA).
        #pragma unroll
        for (int off = 32; off > 0; off >>= 1)
            s += __shfl_xor(s, off, 64);

        s *= (1.0f / OUTPUT_DIM);

        c.x += s; c.y += s; c.z += s; c.w += s;
        d.x += s; d.y += s; d.z += s; d.w += s;

        v4f* orow = o + t * (OUTPUT_DIM / 4);
        __builtin_nontemporal_store(c, &orow[lane]);
        __builtin_nontemporal_store(d, &orow[64 + lane]);
    }
}

extern "C" void kernel_launch(void* const* d_in, const int* in_sizes, int n_in,
                              void* d_out, int out_size, void* d_ws, size_t ws_size,
                              hipStream_t stream) {
    const float* x   = (const float*)d_in[0];
    float*       out = (float*)d_out;

    const int n_rows = in_sizes[0] / IN_DIM;            // 131072

    const int block = 256;                              // 4 waves/block
    const int waves = (n_rows + ROWS_PER_WAVE - 1) / ROWS_PER_WAVE;  // 32768
    const int grid  = (waves + 3) / 4;                  // 8192 blocks

    proj_kernel<<<grid, block, 0, stream>>>(x, out, n_rows);
}